// Round 1
// baseline (1009.086 us; speedup 1.0000x reference)
//
#include <hip/hip_runtime.h>

// RecurrentStickBreakingConstruction — fp32 correct-first implementation.
// K1: serial RNN recurrence (1 block, 512 threads, Wc row in registers,
//     double-buffered h in LDS, one barrier/step).
// K2: fused GEMM (Z @ H^T) + sigmoid + stick-breaking + coalesced store.
//     64 batch rows/block, K staged in LDS chunks of 64, eta kept in LDS,
//     cumprod done in-place, never materialized in HBM.

#define NTOP 256

// ---------------------------------------------------------------- K1
__global__ __launch_bounds__(512) void rsbc_recur(
    const float* __restrict__ Wih, const float* __restrict__ Whh,
    const float* __restrict__ bih, const float* __restrict__ bhh,
    const float* __restrict__ h0, float* __restrict__ H) {
  __shared__ float hA[NTOP], hB[NTOP];
  const int tid  = threadIdx.x;
  const int j    = tid >> 1;     // output index 0..255
  const int half = tid & 1;      // k-chunk 0/1
  const int k0   = half * 128;
  const float bj = bih[j] + bhh[j];

  // row j of W_ih (later Wc = W_ih + W_hh), k0..k0+127, in registers
  float4 w[32];
  const float4* wp = reinterpret_cast<const float4*>(Wih + j * NTOP + k0);
#pragma unroll
  for (int q = 0; q < 32; ++q) w[q] = wp[q];

  if (tid < NTOP) hA[tid] = h0[tid];
  __syncthreads();

  // step 0: h1 = tanh(h0 @ Wih^T + b)  (uses W_ih only)
  {
    float acc = 0.f;
#pragma unroll
    for (int q = 0; q < 32; ++q) {
      float4 hv = *reinterpret_cast<const float4*>(&hA[k0 + 4 * q]);
      acc += hv.x * w[q].x + hv.y * w[q].y + hv.z * w[q].z + hv.w * w[q].w;
    }
    acc += __shfl_xor(acc, 1);
    if (half == 0) {
      float v = tanhf(acc + bj);
      hB[j] = v;
      H[j]  = v;                 // H row 0
    }
  }
  // build Wc = W_ih + W_hh (register add, streamed from global)
  const float4* wq = reinterpret_cast<const float4*>(Whh + j * NTOP + k0);
#pragma unroll
  for (int q = 0; q < 32; ++q) {
    float4 t = wq[q];
    w[q].x += t.x; w[q].y += t.y; w[q].z += t.z; w[q].w += t.w;
  }
  __syncthreads();               // hB (h1) visible; hA reads of step0 done

  for (int s = 1; s < 255; ++s) {
    const float* hr = (s & 1) ? hB : hA;   // read buffer
    float*       hw = (s & 1) ? hA : hB;   // write buffer
    float acc = 0.f;
#pragma unroll
    for (int q = 0; q < 32; ++q) {
      float4 hv = *reinterpret_cast<const float4*>(&hr[k0 + 4 * q]);
      acc += hv.x * w[q].x + hv.y * w[q].y + hv.z * w[q].z + hv.w * w[q].w;
    }
    acc += __shfl_xor(acc, 1);
    if (half == 0) {
      float v = tanhf(acc + bj);
      hw[j] = v;
      H[s * NTOP + j] = v;       // H row s
    }
    __syncthreads();
  }
}

// ---------------------------------------------------------------- K2
// 64 rows/block, 512 threads: thread t -> row r = t>>3, col lane q = t&7,
// cols c = 8*j + q (j=0..31) grouped 4-at-a-time into acc[8] (float4).
// LDS strides padded to 68 floats (16B aligned, conflict-free broadcast).
__global__ __launch_bounds__(512) void rsbc_gemm_sb(
    const float* __restrict__ z, const float* __restrict__ Hm,
    float* __restrict__ out) {
  constexpr int ZS = 68;                // z tile stride (floats)
  constexpr int HS = 68;                // H tile stride
  constexpr int ES = 261;               // eta stride (odd -> bank-friendly)
  __shared__ __align__(16) float smem[64 * ZS + 256 * HS];  // 87,040 B
  __shared__ float logtab[256];
  float* zt  = smem;                    // [64][68]   (phase 1)
  float* Ht  = smem + 64 * ZS;          // [256][68]  (phase 1, row255 = 0)
  float* eta = smem;                    // [64][261]  (phase 2, aliases)

  const int tid  = threadIdx.x;
  const int row0 = blockIdx.x * 64;
  const int r    = tid >> 3;            // 0..63
  const int q    = tid & 7;             // 0..7

  if (tid < 255) logtab[tid] = logf((float)(255 - tid));

  float4 acc[8];
#pragma unroll
  for (int g = 0; g < 8; ++g) acc[g] = make_float4(0.f, 0.f, 0.f, 0.f);

  for (int kk = 0; kk < 4; ++kk) {
    const int kbase = kk * 64;
    __syncthreads();                    // previous chunk's reads complete
    // stage z tile: 64 rows x 16 float4
#pragma unroll
    for (int it = 0; it < 2; ++it) {
      int idx = tid + 512 * it;
      int zr = idx >> 4, kq = idx & 15;
      *reinterpret_cast<float4*>(&zt[zr * ZS + 4 * kq]) =
          *reinterpret_cast<const float4*>(
              &z[(size_t)(row0 + zr) * NTOP + kbase + 4 * kq]);
    }
    // stage H tile: 256 rows x 16 float4 (row 255 zeroed)
#pragma unroll
    for (int it = 0; it < 8; ++it) {
      int idx = tid + 512 * it;
      int hr = idx >> 4, kq = idx & 15;
      float4 v = make_float4(0.f, 0.f, 0.f, 0.f);
      if (hr < 255)
        v = *reinterpret_cast<const float4*>(&Hm[hr * NTOP + kbase + 4 * kq]);
      *reinterpret_cast<float4*>(&Ht[hr * HS + 4 * kq]) = v;
    }
    __syncthreads();
    // compute: 16 k-quads x 8 col-groups x 16 FMA
#pragma unroll 4
    for (int k4 = 0; k4 < 16; ++k4) {
      float4 zv = *reinterpret_cast<const float4*>(&zt[r * ZS + 4 * k4]);
#pragma unroll
      for (int g = 0; g < 8; ++g) {
        float4 a = *reinterpret_cast<const float4*>(&Ht[(32*g      + q) * HS + 4*k4]);
        float4 b = *reinterpret_cast<const float4*>(&Ht[(32*g +  8 + q) * HS + 4*k4]);
        float4 c = *reinterpret_cast<const float4*>(&Ht[(32*g + 16 + q) * HS + 4*k4]);
        float4 d = *reinterpret_cast<const float4*>(&Ht[(32*g + 24 + q) * HS + 4*k4]);
        acc[g].x += zv.x*a.x + zv.y*a.y + zv.z*a.z + zv.w*a.w;
        acc[g].y += zv.x*b.x + zv.y*b.y + zv.z*b.z + zv.w*b.w;
        acc[g].z += zv.x*c.x + zv.y*c.y + zv.z*c.z + zv.w*c.w;
        acc[g].w += zv.x*d.x + zv.y*d.y + zv.z*d.z + zv.w*d.w;
      }
    }
  }
  __syncthreads();                      // all GEMM LDS reads done -> reuse as eta

  // eta = sigmoid(logits) -> LDS (col 255 is a dummy, never read)
#pragma unroll
  for (int g = 0; g < 8; ++g) {
    int cb = 32 * g;
    eta[r * ES + cb      + q] = 1.f / (1.f + expf(-acc[g].x));
    eta[r * ES + cb +  8 + q] = 1.f / (1.f + expf(-acc[g].y));
    eta[r * ES + cb + 16 + q] = 1.f / (1.f + expf(-acc[g].z));
    eta[r * ES + cb + 24 + q] = 1.f / (1.f + expf(-acc[g].w));
  }
  __syncthreads();

  // stick-breaking: one thread per row, cumprod in place over eta row
  if (tid < 64) {
    float cp = 1.f;
    float* er = &eta[tid * ES];
#pragma unroll 4
    for (int k = 0; k < 255; ++k) {
      float x  = er[k] - logtab[k];
      float zc = 1.f / (1.f + expf(-x));
      zc = fminf(fmaxf(zc, 1.1754943508222875e-38f), 0.99999988079071045f);
      er[k] = zc * cp;          // out[k] = zc * cumprod_{<k}(1-zc)
      cp *= 1.f - zc;
    }
    er[255] = cp;               // out[255] = full cumprod
  }
  __syncthreads();

  // coalesced store: 64 rows x 64 float4
#pragma unroll
  for (int it = 0; it < 8; ++it) {
    int idx = tid + 512 * it;           // 0..4095
    int rr = idx >> 6, cq = idx & 63;
    const float* e = &eta[rr * ES + 4 * cq];
    float4 v; v.x = e[0]; v.y = e[1]; v.z = e[2]; v.w = e[3];
    *reinterpret_cast<float4*>(&out[(size_t)(row0 + rr) * NTOP + 4 * cq]) = v;
  }
}

// ---------------------------------------------------------------- launch
extern "C" void kernel_launch(void* const* d_in, const int* in_sizes, int n_in,
                              void* d_out, int out_size, void* d_ws, size_t ws_size,
                              hipStream_t stream) {
  const float* z   = (const float*)d_in[0];
  const float* h0  = (const float*)d_in[1];
  const float* Wih = (const float*)d_in[2];
  const float* Whh = (const float*)d_in[3];
  const float* bih = (const float*)d_in[4];
  const float* bhh = (const float*)d_in[5];
  float* out = (float*)d_out;
  float* H   = (float*)d_ws;            // 255*256 floats = 261,120 B scratch

  rsbc_recur<<<1, 512, 0, stream>>>(Wih, Whh, bih, bhh, h0, H);
  const int nrows  = out_size / NTOP;   // 131072
  const int blocks = nrows / 64;        // 2048
  rsbc_gemm_sb<<<blocks, 512, 0, stream>>>(z, H, out);
}

// Round 2
// 335.055 us; speedup vs baseline: 3.0117x; 3.0117x over previous
//
#include <hip/hip_runtime.h>

#define NTOP 256

typedef __attribute__((ext_vector_type(8))) short bf16x8;
typedef __attribute__((ext_vector_type(4))) float f32x4;

// round-to-nearest-even split of fp32 into bf16 hi/lo, packed (hi<<16)|lo
__device__ inline unsigned int packbf(float x) {
  unsigned int u = __float_as_uint(x);
  unsigned int r = (u + 0x7fffu + ((u >> 16) & 1u)) & 0xffff0000u;
  float res = x - __uint_as_float(r);
  unsigned int u2 = __float_as_uint(res);
  unsigned int r2 = u2 + 0x7fffu + ((u2 >> 16) & 1u);
  return r | (r2 >> 16);
}

__device__ inline float tanh_fast(float x) {
  float e = __expf(2.f * x);
  return 1.f - 2.f / (e + 1.f);
}

// ---------------------------------------------------------------- K1
// 1024 threads: j = tid>>2 (output idx), qt = tid&3 (k-quarter of 64).
// Wc row quarter in regs (16 float4), h double-buffered in padded LDS
// ([4][68] so the 4 broadcast addresses hit different banks).
// 4 accumulators break the FMA dependency chain.
__global__ __launch_bounds__(1024) void rsbc_recur(
    const float* __restrict__ Wih, const float* __restrict__ Whh,
    const float* __restrict__ bih, const float* __restrict__ bhh,
    const float* __restrict__ h0, unsigned int* __restrict__ Hpack) {
  __shared__ float hA[4][68], hB[4][68];
  const int tid = threadIdx.x;
  const int j = tid >> 2, qt = tid & 3, k0 = qt * 64;
  const float bj = bih[j] + bhh[j];

  float4 w[16];
  const float4* wp = reinterpret_cast<const float4*>(Wih + j * NTOP + k0);
#pragma unroll
  for (int q = 0; q < 16; ++q) w[q] = wp[q];

  if (tid < NTOP) hA[tid >> 6][tid & 63] = h0[tid];
  __syncthreads();

  // step 0: h1 = tanh(h0 @ Wih^T + b)
  {
    const float* hq = hA[qt];
    float a0 = 0.f, a1 = 0.f, a2 = 0.f, a3 = 0.f;
#pragma unroll
    for (int q = 0; q < 16; ++q) {
      float4 hv = *reinterpret_cast<const float4*>(hq + 4 * q);
      a0 += hv.x * w[q].x; a1 += hv.y * w[q].y;
      a2 += hv.z * w[q].z; a3 += hv.w * w[q].w;
    }
    float s = (a0 + a1) + (a2 + a3);
    s += __shfl_xor(s, 1);
    s += __shfl_xor(s, 2);
    if (qt == 0) {
      float v = tanh_fast(s + bj);
      hB[j >> 6][j & 63] = v;
      Hpack[j] = packbf(v);            // H row 0
    }
  }
  // Wc = W_ih + W_hh
  const float4* wq = reinterpret_cast<const float4*>(Whh + j * NTOP + k0);
#pragma unroll
  for (int q = 0; q < 16; ++q) {
    float4 t = wq[q];
    w[q].x += t.x; w[q].y += t.y; w[q].z += t.z; w[q].w += t.w;
  }
  __syncthreads();

  for (int s = 1; s < 255; ++s) {
    const float(*hr)[68] = (s & 1) ? hB : hA;
    float(*hw)[68] = (s & 1) ? hA : hB;
    const float* hq = hr[qt];
    float a0 = 0.f, a1 = 0.f, a2 = 0.f, a3 = 0.f;
#pragma unroll
    for (int q = 0; q < 16; ++q) {
      float4 hv = *reinterpret_cast<const float4*>(hq + 4 * q);
      a0 += hv.x * w[q].x; a1 += hv.y * w[q].y;
      a2 += hv.z * w[q].z; a3 += hv.w * w[q].w;
    }
    float sv = (a0 + a1) + (a2 + a3);
    sv += __shfl_xor(sv, 1);
    sv += __shfl_xor(sv, 2);
    if (qt == 0) {
      float v = tanh_fast(sv + bj);
      hw[j >> 6][j & 63] = v;
      Hpack[s * NTOP + j] = packbf(v); // H row s
    }
    __syncthreads();
  }
}

// ---------------------------------------------------------------- K2
// bf16x3-split MFMA GEMM (Z @ H^T) + sigmoid + stick-breaking, fused.
// Block: 512 threads (8 waves, 2x4 wave grid), BM=128 rows, N=256 cols,
// K=256 in 4 chunks of 64. A (z) converted fp32->bf16 hi/lo on the fly;
// B (H) pre-split by K1 into packed uint32. Epilogue: eta in LDS (stride
// 260), 4-thread segmented cumprod, float4 store.
__global__ __launch_bounds__(512, 2) void rsbc_gemm_sb(
    const float* __restrict__ z, const unsigned int* __restrict__ Hpack,
    float* __restrict__ out) {
  constexpr int AS = 72;   // A row stride (bf16 elems), 144 B
  constexpr int BS = 72;   // B row stride
  constexpr int ES = 260;  // eta row stride (floats), 1040 B, 16B-aligned
  // staging: (128*72 + 256*72) ushort * 2(hi,lo) = 110,592 B
  // eta    : 128*260*4 + segT 128*4*4            = 135,168 B
  __shared__ __align__(16) char smem[135168];
  __shared__ float logtab[256];
  ushort* Ahi = reinterpret_cast<ushort*>(smem);
  ushort* Alo = Ahi + 128 * AS;
  ushort* Bhi = Alo + 128 * AS;
  ushort* Blo = Bhi + 256 * BS;
  float* eta = reinterpret_cast<float*>(smem);
  float* segT = eta + 128 * ES;

  const int tid = threadIdx.x;
  const size_t row0 = (size_t)blockIdx.x * 128;
  const int wid = tid >> 6, lane = tid & 63;
  const int wr = wid >> 2, wc = wid & 3;
  const int l15 = lane & 15, l4 = lane >> 4;

  if (tid < 255) logtab[tid] = logf((float)(255 - tid));

  f32x4 acc[4][4];
#pragma unroll
  for (int mt = 0; mt < 4; ++mt)
#pragma unroll
    for (int nt = 0; nt < 4; ++nt) acc[mt][nt] = (f32x4){0.f, 0.f, 0.f, 0.f};

  for (int kc = 0; kc < 4; ++kc) {
    const int kb = kc * 64;
    // ---- global loads into regs (issued before barrier: overlap w/ compute)
    float4 zreg[4];
#pragma unroll
    for (int it = 0; it < 4; ++it) {
      int idx = tid + 512 * it;        // 0..2047
      int r = idx >> 4, q = idx & 15;  // r 0..127
      zreg[it] = *reinterpret_cast<const float4*>(
          z + (row0 + r) * NTOP + kb + 4 * q);
    }
    uint4 hreg[8];
#pragma unroll
    for (int it = 0; it < 8; ++it) {
      int idx = tid + 512 * it;        // 0..4095
      int r = idx >> 4, q = idx & 15;  // r 0..255
      hreg[it] = (r < 255)
                     ? *reinterpret_cast<const uint4*>(
                           Hpack + r * NTOP + kb + 4 * q)
                     : make_uint4(0u, 0u, 0u, 0u);
    }
    __syncthreads();                   // previous chunk's frag reads done
    // ---- convert + LDS write
#pragma unroll
    for (int it = 0; it < 4; ++it) {
      int idx = tid + 512 * it;
      int r = idx >> 4, q = idx & 15;
      float4 v = zreg[it];
      unsigned int p0 = packbf(v.x), p1 = packbf(v.y),
                   p2 = packbf(v.z), p3 = packbf(v.w);
      *reinterpret_cast<ushort4*>(&Ahi[r * AS + 4 * q]) = make_ushort4(
          (ushort)(p0 >> 16), (ushort)(p1 >> 16),
          (ushort)(p2 >> 16), (ushort)(p3 >> 16));
      *reinterpret_cast<ushort4*>(&Alo[r * AS + 4 * q]) = make_ushort4(
          (ushort)(p0 & 0xffff), (ushort)(p1 & 0xffff),
          (ushort)(p2 & 0xffff), (ushort)(p3 & 0xffff));
    }
#pragma unroll
    for (int it = 0; it < 8; ++it) {
      int idx = tid + 512 * it;
      int r = idx >> 4, q = idx & 15;
      uint4 hv = hreg[it];
      *reinterpret_cast<ushort4*>(&Bhi[r * BS + 4 * q]) = make_ushort4(
          (ushort)(hv.x >> 16), (ushort)(hv.y >> 16),
          (ushort)(hv.z >> 16), (ushort)(hv.w >> 16));
      *reinterpret_cast<ushort4*>(&Blo[r * BS + 4 * q]) = make_ushort4(
          (ushort)(hv.x & 0xffff), (ushort)(hv.y & 0xffff),
          (ushort)(hv.z & 0xffff), (ushort)(hv.w & 0xffff));
    }
    __syncthreads();                   // staging visible
    // ---- compute: 2 k-steps of K=32
#pragma unroll
    for (int ks = 0; ks < 2; ++ks) {
      const int ko = ks * 32 + l4 * 8; // k elem offset within chunk row
      bf16x8 afh[4], afl[4], bfh[4], bfl[4];
#pragma unroll
      for (int mt = 0; mt < 4; ++mt) {
        int r = 64 * wr + 16 * mt + l15;
        afh[mt] = *reinterpret_cast<const bf16x8*>(&Ahi[r * AS + ko]);
        afl[mt] = *reinterpret_cast<const bf16x8*>(&Alo[r * AS + ko]);
      }
#pragma unroll
      for (int nt = 0; nt < 4; ++nt) {
        int n = 64 * wc + 16 * nt + l15;
        bfh[nt] = *reinterpret_cast<const bf16x8*>(&Bhi[n * BS + ko]);
        bfl[nt] = *reinterpret_cast<const bf16x8*>(&Blo[n * BS + ko]);
      }
#pragma unroll
      for (int mt = 0; mt < 4; ++mt)
#pragma unroll
        for (int nt = 0; nt < 4; ++nt) {
          acc[mt][nt] = __builtin_amdgcn_mfma_f32_16x16x32_bf16(
              afh[mt], bfh[nt], acc[mt][nt], 0, 0, 0);
          acc[mt][nt] = __builtin_amdgcn_mfma_f32_16x16x32_bf16(
              afh[mt], bfl[nt], acc[mt][nt], 0, 0, 0);
          acc[mt][nt] = __builtin_amdgcn_mfma_f32_16x16x32_bf16(
              afl[mt], bfh[nt], acc[mt][nt], 0, 0, 0);
        }
    }
  }
  __syncthreads();                     // frag reads done; smem becomes eta

  // ---- eta = sigmoid(logits) -> LDS
  // C/D layout (16x16x32): col = lane&15, row = (lane>>4)*4 + reg
#pragma unroll
  for (int mt = 0; mt < 4; ++mt) {
    int rbase = 64 * wr + 16 * mt + 4 * l4;
#pragma unroll
    for (int nt = 0; nt < 4; ++nt) {
      int c = 64 * wc + 16 * nt + l15;
#pragma unroll
      for (int i = 0; i < 4; ++i) {
        float x = acc[mt][nt][i];
        eta[(rbase + i) * ES + c] = 1.f / (1.f + __expf(-x));
      }
    }
  }
  __syncthreads();

  // ---- stick-breaking: 4 threads per row, segmented cumprod
  const int r = tid >> 2, qk = tid & 3;
  const int kbeg = 64 * qk, kend = (qk == 3) ? 255 : 64 * qk + 64;
  float* er = &eta[r * ES];
  {
    float cp = 1.f;
#pragma unroll 4
    for (int k = kbeg; k < kend; ++k) {
      float x = er[k] - logtab[k];
      float zc = 1.f / (1.f + __expf(-x));
      zc = fminf(fmaxf(zc, 1.1754943508222875e-38f), 0.99999988079071045f);
      er[k] = zc * cp;
      cp *= 1.f - zc;
    }
    segT[r * 4 + qk] = cp;
  }
  __syncthreads();
  {
    float p = 1.f;
    if (qk > 0) p *= segT[r * 4 + 0];
    if (qk > 1) p *= segT[r * 4 + 1];
    if (qk > 2) p *= segT[r * 4 + 2];
    if (qk > 0) {
#pragma unroll 4
      for (int k = kbeg; k < kend; ++k) er[k] *= p;
    }
    if (qk == 3) er[255] = p * segT[r * 4 + 3];
  }
  __syncthreads();

  // ---- coalesced store: 128 rows x 64 float4
#pragma unroll
  for (int it = 0; it < 16; ++it) {
    int idx = tid + 512 * it;          // 0..8191
    int rr = idx >> 6, cq = idx & 63;
    float4 vv = *reinterpret_cast<const float4*>(&eta[rr * ES + 4 * cq]);
    *reinterpret_cast<float4*>(&out[(row0 + rr) * NTOP + 4 * cq]) = vv;
  }
}

// ---------------------------------------------------------------- launch
extern "C" void kernel_launch(void* const* d_in, const int* in_sizes, int n_in,
                              void* d_out, int out_size, void* d_ws, size_t ws_size,
                              hipStream_t stream) {
  const float* z   = (const float*)d_in[0];
  const float* h0  = (const float*)d_in[1];
  const float* Wih = (const float*)d_in[2];
  const float* Whh = (const float*)d_in[3];
  const float* bih = (const float*)d_in[4];
  const float* bhh = (const float*)d_in[5];
  float* out = (float*)d_out;
  unsigned int* Hpack = (unsigned int*)d_ws;  // 255*256 uint32 = 261,120 B

  rsbc_recur<<<1, 1024, 0, stream>>>(Wih, Whh, bih, bhh, h0, Hpack);
  const int nrows = out_size / NTOP;          // 131072
  const int blocks = nrows / 128;             // 1024
  rsbc_gemm_sb<<<blocks, 512, 0, stream>>>(z, Hpack, out);
}